// Round 1
// 863.089 us; speedup vs baseline: 3.1527x; 3.1527x over previous
//
#include <hip/hip_runtime.h>
#include <hip/hip_bf16.h>

#define B 4
#define S 1024
#define D 768
#define H 12
#define HD 64
#define MROWS (B * S)          // 4096
#define NELEM (B * S * D)      // 3145728

typedef __attribute__((ext_vector_type(8))) short short8;
typedef __attribute__((ext_vector_type(4))) float f32x4;

#define MFMA16(a, b, c) __builtin_amdgcn_mfma_f32_16x16x32_bf16(a, b, c, 0, 0, 0)

static __device__ __forceinline__ float bs2f(short s) {
    unsigned int u = ((unsigned int)(unsigned short)s) << 16;
    float f;
    __builtin_memcpy(&f, &u, 4);
    return f;
}
static __device__ __forceinline__ short f2bs(float f) {
    __hip_bfloat16 h = __float2bfloat16(f);
    return __builtin_bit_cast(short, h);
}
static __device__ __forceinline__ float loadin(const void* p, size_t i, int isb) {
    return isb ? bs2f(((const short*)p)[i]) : ((const float*)p)[i];
}

// ======================= dtype detect =======================
__global__ void detect_k(const void* p, int* flag) {
    if (threadIdx.x == 0 && blockIdx.x == 0) {
        const short* hb = (const short*)p;
        int insane = 0;
        for (int i = 0; i < 512; i += 2) {
            float v = bs2f(hb[i]);
            if (!(v == v) || fabsf(v) > 1e3f || (v != 0.0f && fabsf(v) < 1e-20f)) insane++;
        }
        *flag = (insane > 64) ? 0 : 1;
    }
}

// ======================= embed + positional (dual fp32 + bf16) =======================
__global__ __launch_bounds__(256) void embed_pos_k(const int* __restrict__ x,
                                                   const void* __restrict__ embed,
                                                   float* __restrict__ outf,
                                                   short* __restrict__ outb,
                                                   const int* __restrict__ flg) {
    const int f = *flg;
    int bs = blockIdx.x;
    int tok = x[bs];
    int s = bs & (S - 1);
    for (int j = threadIdx.x; j < D; j += 256) {
        float e = loadin(embed, (size_t)tok * D + j, f);
        int i = j >> 1;
        float ang = (float)s * __expf(-9.210340371976184f * (2.0f * (float)i) / (float)D);
        float p = (j & 1) ? cosf(ang) : sinf(ang);
        float v = 2.0f * e + p;
        outf[bs * D + j] = v;
        outb[bs * D + j] = f2bs(v);
    }
}

// any-dtype -> bf16
__global__ __launch_bounds__(256) void cvt2b_k(const void* __restrict__ in,
                                               short* __restrict__ out, int n,
                                               const int* __restrict__ flg) {
    const int f = *flg;
    int i = blockIdx.x * 256 + threadIdx.x;
    if (i < n) out[i] = f2bs(loadin(in, i, f));
}

// final store: fp32 state -> out dtype per flag
__global__ __launch_bounds__(256) void store_out_f(const float* __restrict__ in,
                                                   void* __restrict__ out, int n,
                                                   const int* __restrict__ flg) {
    const int f = *flg;
    int i = blockIdx.x * 256 + threadIdx.x;
    if (i < n) {
        if (f) ((short*)out)[i] = f2bs(in[i]);
        else   ((float*)out)[i] = in[i];
    }
}

// ======================= weight transpose-convert: W[K][768] -> WT bf16 [768][K] =======================
__global__ __launch_bounds__(256) void wtrans_k(const void* __restrict__ src,
                                                short* __restrict__ dst, int K,
                                                const int* __restrict__ flg) {
    const int f = *flg;
    __shared__ __align__(16) short Ts[64 * 72];
    int n0 = blockIdx.x * 64;
    int k0 = blockIdx.y * 64;
    int t = threadIdx.x;
    int r = t >> 2, c4 = (t & 3) * 16;
    #pragma unroll
    for (int j = 0; j < 16; j++)
        Ts[r * 72 + c4 + j] = f2bs(loadin(src, (size_t)(k0 + r) * D + n0 + c4 + j, f));
    __syncthreads();
    int n = t >> 2, kc = (t & 3) * 16;
    short tmp[16];
    #pragma unroll
    for (int j = 0; j < 16; j++) tmp[j] = Ts[(kc + j) * 72 + n];
    short* dchunk = dst + (size_t)(n0 + n) * K + k0 + kc;
    *(short8*)&dchunk[0] = *(const short8*)&tmp[0];
    *(short8*)&dchunk[8] = *(const short8*)&tmp[8];
}

// ======================= bf16 V [B,H,S,64] -> [B,H,64,S] =======================
__global__ __launch_bounds__(256) void cvtT_vb_k(const short* __restrict__ in,
                                                 short* __restrict__ out) {
    __shared__ __align__(16) short Ts[64 * 72];
    int s0 = blockIdx.x * 64;
    int bh = blockIdx.y;
    int t = threadIdx.x;
    int r = t >> 2, c4 = (t & 3) * 16;
    const short* src = in + ((size_t)bh * S + s0 + r) * HD + c4;
    *(short8*)&Ts[r * 72 + c4] = *(const short8*)&src[0];
    *(short8*)&Ts[r * 72 + c4 + 8] = *(const short8*)&src[8];
    __syncthreads();
    int hd = t >> 2, sc = (t & 3) * 16;
    short tmp[16];
    #pragma unroll
    for (int j = 0; j < 16; j++) tmp[j] = Ts[(sc + j) * 72 + hd];
    short* dst = out + ((size_t)bh * HD + hd) * S + s0 + sc;
    *(short8*)&dst[0] = *(const short8*)&tmp[0];
    *(short8*)&dst[8] = *(const short8*)&tmp[8];
}

// ======================= MFMA GEMM (validated structure) =======================
// A bf16 [4096][lda], WT bf16 [768][K]. mode: 0=flat bf16, 1=head bf16, 2=flat fp32
__global__ __launch_bounds__(256) void mgemm_k(const short* __restrict__ A, int lda,
                                               const short* __restrict__ WT, int K,
                                               const void* __restrict__ bias,
                                               void* __restrict__ out,
                                               int relu, int mode,
                                               const int* __restrict__ flg) {
    const int f = *flg;
    __shared__ __align__(16) short As[128 * 32];
    __shared__ __align__(16) short Bs[64 * 32];
    const int t = threadIdx.x;
    const int wave = t >> 6, lane = t & 63;
    const int quad = lane >> 4, l16 = lane & 15;
    const int n0 = blockIdx.x * 64;
    const int m0 = blockIdx.y * 128;
    const int wm = (wave >> 1) * 64;
    const int wn = (wave & 1) * 32;
    f32x4 acc[4][2];
    #pragma unroll
    for (int i = 0; i < 4; i++)
        #pragma unroll
        for (int j = 0; j < 2; j++) acc[i][j] = f32x4{0.f, 0.f, 0.f, 0.f};

    const int ar0 = t >> 2;
    const int ac = (t & 3) * 8;
    const int br = t >> 2;
    for (int k0 = 0; k0 < K; k0 += 32) {
        *(short8*)&As[ar0 * 32 + ac] =
            *(const short8*)&A[(size_t)(m0 + ar0) * lda + k0 + ac];
        *(short8*)&As[(ar0 + 64) * 32 + ac] =
            *(const short8*)&A[(size_t)(m0 + ar0 + 64) * lda + k0 + ac];
        *(short8*)&Bs[br * 32 + ac] =
            *(const short8*)&WT[(size_t)(n0 + br) * K + k0 + ac];
        __syncthreads();
        short8 af[4], bfr[2];
        #pragma unroll
        for (int i = 0; i < 4; i++)
            af[i] = *(const short8*)&As[(wm + i * 16 + l16) * 32 + quad * 8];
        #pragma unroll
        for (int j = 0; j < 2; j++)
            bfr[j] = *(const short8*)&Bs[(wn + j * 16 + l16) * 32 + quad * 8];
        #pragma unroll
        for (int i = 0; i < 4; i++)
            #pragma unroll
            for (int j = 0; j < 2; j++)
                acc[i][j] = MFMA16(af[i], bfr[j], acc[i][j]);
        __syncthreads();
    }
    #pragma unroll
    for (int j = 0; j < 2; j++) {
        int col = n0 + wn + j * 16 + l16;
        float bv = loadin(bias, col, f);
        #pragma unroll
        for (int i = 0; i < 4; i++) {
            int rowb = m0 + wm + i * 16 + quad * 4;
            #pragma unroll
            for (int r = 0; r < 4; r++) {
                float v = acc[i][j][r] + bv;
                if (relu) v = fmaxf(v, 0.f);
                int row = rowb + r;
                if (mode == 2) {
                    ((float*)out)[(size_t)row * D + col] = v;
                } else if (mode == 1) {
                    size_t idx = (((size_t)(row >> 10) * H + (col >> 6)) * S + (row & (S - 1))) * HD + (col & 63);
                    ((short*)out)[idx] = f2bs(v);
                } else {
                    ((short*)out)[(size_t)row * D + col] = f2bs(v);
                }
            }
        }
    }
}

// ======================= batch-norm =======================
__global__ __launch_bounds__(256) void bnstat_f(const float* __restrict__ a,
                                                const float* __restrict__ b,
                                                float* __restrict__ part) {
    __shared__ float ls[8][32];
    __shared__ float ls2[8][32];
    int f = blockIdx.x * 32 + (threadIdx.x & 31);
    int rg = threadIdx.x >> 5;
    int r0 = blockIdx.y * 256;
    float s = 0.f, s2 = 0.f;
    for (int r = r0 + rg; r < r0 + 256; r += 8) {
        float v = a[(size_t)r * D + f] + b[(size_t)r * D + f];
        s += v;
        s2 += v * v;
    }
    ls[rg][threadIdx.x & 31] = s;
    ls2[rg][threadIdx.x & 31] = s2;
    __syncthreads();
    if (threadIdx.x < 32) {
        float ts = 0.f, ts2 = 0.f;
        #pragma unroll
        for (int i = 0; i < 8; i++) { ts += ls[i][threadIdx.x]; ts2 += ls2[i][threadIdx.x]; }
        part[blockIdx.y * D + blockIdx.x * 32 + threadIdx.x] = ts;
        part[16 * D + blockIdx.y * D + blockIdx.x * 32 + threadIdx.x] = ts2;
    }
}

__global__ __launch_bounds__(256) void bnfin_k(const float* __restrict__ part,
                                               float* __restrict__ stats) {
    int f = blockIdx.x * 256 + threadIdx.x;
    if (f < D) {
        float s = 0.f, s2 = 0.f;
        #pragma unroll
        for (int i = 0; i < 16; i++) { s += part[i * D + f]; s2 += part[16 * D + i * D + f]; }
        float mean = s * (1.0f / (float)MROWS);
        float var = s2 * (1.0f / (float)MROWS) - mean * mean;
        stats[f] = mean;
        stats[D + f] = rsqrtf(var + 1e-5f);
    }
}

// dual-output bn apply: fp32 master + bf16 operand copy
__global__ __launch_bounds__(256) void bnapply_k(const float* __restrict__ a,
                                                 const float* __restrict__ b,
                                                 const float* __restrict__ stats,
                                                 const void* __restrict__ g,
                                                 const void* __restrict__ beta,
                                                 float* __restrict__ outf,
                                                 short* __restrict__ outb, int n,
                                                 const int* __restrict__ flg) {
    const int fl = *flg;
    int i = blockIdx.x * 256 + threadIdx.x;
    if (i < n) {
        int f = i % D;
        float v = a[i] + b[i];
        float y = (v - stats[f]) * stats[D + f] * loadin(g, f, fl) + loadin(beta, f, fl);
        outf[i] = y;
        outb[i] = f2bs(y);
    }
}

// ======================= MFMA flash attention (bf16 in; fp32 or bf16 out) =======================
__global__ __launch_bounds__(256) void mfma_attn_fo_k(const short* __restrict__ Q,
                                                      const short* __restrict__ Km,
                                                      const short* __restrict__ Vt,
                                                      void* __restrict__ out, float scale,
                                                      int obf) {
    __shared__ __align__(16) short Ks[64 * 64];
    __shared__ __align__(16) short Vs[64 * 64];
    __shared__ __align__(16) short Ps[4][16 * 72];
    const int qt = blockIdx.x;
    const int bh = blockIdx.y;
    const int b = bh / H, h = bh % H;
    const int t = threadIdx.x;
    const int wave = t >> 6, lane = t & 63, quad = lane >> 4, l16 = lane & 15;
    const short* Qh = Q + (size_t)bh * S * HD;
    const short* Kh = Km + (size_t)bh * S * HD;
    const short* Vh = Vt + (size_t)bh * S * HD;
    const int qrow = qt * 64 + wave * 16 + l16;
    short8 qf0 = *(const short8*)&Qh[(size_t)qrow * 64 + quad * 8];
    short8 qf1 = *(const short8*)&Qh[(size_t)qrow * 64 + 32 + quad * 8];
    f32x4 o[4];
    float m_i[4], l_i[4];
    #pragma unroll
    for (int nt = 0; nt < 4; nt++) o[nt] = f32x4{0.f, 0.f, 0.f, 0.f};
    #pragma unroll
    for (int r = 0; r < 4; r++) { m_i[r] = -1e30f; l_i[r] = 0.f; }
    const int vhd = t >> 2, vkc = (t & 3) * 16;
    const int kidx = t * 16;

    for (int kt = 0; kt < S; kt += 64) {
        *(short8*)&Ks[kidx] = *(const short8*)&Kh[(size_t)kt * 64 + kidx];
        *(short8*)&Ks[kidx + 8] = *(const short8*)&Kh[(size_t)kt * 64 + kidx + 8];
        const short* vsrc = &Vh[(size_t)vhd * S + kt + vkc];
        *(short8*)&Vs[vhd * 64 + vkc] = *(const short8*)&vsrc[0];
        *(short8*)&Vs[vhd * 64 + vkc + 8] = *(const short8*)&vsrc[8];
        __syncthreads();
        f32x4 sf[4];
        #pragma unroll
        for (int nt = 0; nt < 4; nt++) {
            short8 kb0 = *(const short8*)&Ks[(nt * 16 + l16) * 64 + quad * 8];
            short8 kb1 = *(const short8*)&Ks[(nt * 16 + l16) * 64 + 32 + quad * 8];
            f32x4 c = f32x4{0.f, 0.f, 0.f, 0.f};
            c = MFMA16(qf0, kb0, c);
            c = MFMA16(qf1, kb1, c);
            #pragma unroll
            for (int r = 0; r < 4; r++) c[r] *= scale;
            sf[nt] = c;
        }
        #pragma unroll
        for (int r = 0; r < 4; r++) {
            float mx = fmaxf(fmaxf(sf[0][r], sf[1][r]), fmaxf(sf[2][r], sf[3][r]));
            mx = fmaxf(mx, __shfl_xor(mx, 1));
            mx = fmaxf(mx, __shfl_xor(mx, 2));
            mx = fmaxf(mx, __shfl_xor(mx, 4));
            mx = fmaxf(mx, __shfl_xor(mx, 8));
            float mnew = fmaxf(m_i[r], mx);
            float alpha = __expf(m_i[r] - mnew);
            m_i[r] = mnew;
            float rs = 0.f;
            #pragma unroll
            for (int nt = 0; nt < 4; nt++) {
                float p = __expf(sf[nt][r] - mnew);
                sf[nt][r] = p;
                rs += p;
            }
            rs += __shfl_xor(rs, 1);
            rs += __shfl_xor(rs, 2);
            rs += __shfl_xor(rs, 4);
            rs += __shfl_xor(rs, 8);
            l_i[r] = l_i[r] * alpha + rs;
            #pragma unroll
            for (int nt = 0; nt < 4; nt++) o[nt][r] *= alpha;
        }
        #pragma unroll
        for (int nt = 0; nt < 4; nt++)
            #pragma unroll
            for (int r = 0; r < 4; r++)
                Ps[wave][(quad * 4 + r) * 72 + nt * 16 + l16] = f2bs(sf[nt][r]);
        short8 pa0 = *(const short8*)&Ps[wave][l16 * 72 + quad * 8];
        short8 pa1 = *(const short8*)&Ps[wave][l16 * 72 + 32 + quad * 8];
        #pragma unroll
        for (int nt = 0; nt < 4; nt++) {
            short8 vb0 = *(const short8*)&Vs[(nt * 16 + l16) * 64 + quad * 8];
            short8 vb1 = *(const short8*)&Vs[(nt * 16 + l16) * 64 + 32 + quad * 8];
            o[nt] = MFMA16(pa0, vb0, o[nt]);
            o[nt] = MFMA16(pa1, vb1, o[nt]);
        }
        __syncthreads();
    }
    #pragma unroll
    for (int r = 0; r < 4; r++) {
        float inv = 1.0f / l_i[r];
        int row = b * S + qt * 64 + wave * 16 + quad * 4 + r;
        #pragma unroll
        for (int nt = 0; nt < 4; nt++) {
            size_t idx = (size_t)row * D + h * HD + nt * 16 + l16;
            float v = o[nt][r] * inv;
            if (obf) ((short*)out)[idx] = f2bs(v);
            else     ((float*)out)[idx] = v;
        }
    }
}

extern "C" void kernel_launch(void* const* d_in, const int* in_sizes, int n_in,
                              void* d_out, int out_size, void* d_ws, size_t ws_size,
                              hipStream_t stream) {
    const int* x = (const int*)d_in[0];
    const short* encod = (const short*)d_in[1];
    const short* embed = (const short*)d_in[2];
    const short* Wq = (const short*)d_in[3];
    const short* bq = (const short*)d_in[4];
    const short* Wk = (const short*)d_in[5];
    const short* bk = (const short*)d_in[6];
    const short* Wv = (const short*)d_in[7];
    const short* bv = (const short*)d_in[8];
    const short* g1 = (const short*)d_in[9];
    const short* b1 = (const short*)d_in[10];
    const short* Wq2 = (const short*)d_in[11];
    const short* bq2 = (const short*)d_in[12];
    const short* Wk2 = (const short*)d_in[13];
    const short* bk2 = (const short*)d_in[14];
    const short* Wv2 = (const short*)d_in[15];
    const short* bv2 = (const short*)d_in[16];
    const short* Wo2 = (const short*)d_in[17];
    const short* bo2 = (const short*)d_in[18];
    const short* g2 = (const short*)d_in[19];
    const short* b2 = (const short*)d_in[20];
    const short* Wf = (const short*)d_in[21];
    const short* bf_ = (const short*)d_in[22];

    // ---- workspace layout in half-BUF (hb = NELEM shorts) units; total 18 hb = proven 9-slot fp32 footprint ----
    short* HBase = (short*)d_ws;
    #define HB(i) (HBase + (size_t)(i) * NELEM)
    float* IMf = (float*)HB(0);        // hb0-1  fp32 input_multi / final state
    short* IMb = HB(2);                // hb2    bf16 operand copy of IMf
    short* Q2h = HB(3);                // hb3    persistent cross Q (bf16 head layout)
    short* K2h = HB(4);                // hb4    persistent cross K
    short* WTp = HB(5);                // hb5    packed transposed bf16 weights (2949120 shorts < NELEM)
    short* WTq  = WTp;                 // [768][256]
    short* WTk  = WTp + 196608;
    short* WTv  = WTp + 393216;
    short* WTq2 = WTp + 589824;        // [768][384]
    short* WTk2 = WTp + 884736;
    short* WTv2 = WTp + 1179648;       // [768][768]
    short* WTo2 = WTp + 1769472;
    short* WTf  = WTp + 2359296;
    short* Qbh = HB(6);                // hb6    self Q (bf16 head); also Eb pre-loop; also Ub later
    short* Kbh = HB(7);                // hb7    self K
    short* Vbh = HB(8);                // hb8    V proj (head layout)
    short* Vth = HB(9);                // hb9    V transposed [B,H,64,S]
    float* T1f = (float*)HB(10);       // hb10-11 self-attn out fp32; later Uf (t2 fp32)
    float* Tf  = (float*)HB(12);       // hb12-13 t fp32
    short* Tb  = HB(14);               // hb14   t bf16
    short* A2b = HB(15);               // hb15   cross-attn out bf16
    float* T2f = (float*)HB(16);       // hb16-17 m2 fp32
    short* Eb  = Qbh;                  // pre-loop: encod bf16
    float* Uf  = T1f;                  // t2 fp32 (self-attn out dead after BN1)
    short* Ub  = Qbh;                  // t2 bf16 (Qbh dead after self-attn)
    float* Ff  = (float*)HB(8);        // ffn out fp32 (Vbh/Vth dead after cross-attn)
    float* fstats = (float*)HB(18);    // beyond 9 BUF, same as proven layout
    float* fpart  = fstats + 2048;
    int*   flg    = (int*)(fpart + 2 * 16 * D);

    const dim3 mGrid(D / 64, MROWS / 128);   // 12 x 32
    const dim3 bnGridF(D / 32, 16);
    const dim3 aGrid(S / 64, B * H);
    const int EB = (NELEM + 255) / 256;
    const float scale1 = 0.03608439182435161f;   // 1/sqrt(768)
    const float scale2 = 0.125f;                 // 1/sqrt(64)

    detect_k<<<1, 64, 0, stream>>>(encod, flg);
    embed_pos_k<<<MROWS, 256, 0, stream>>>(x, embed, IMf, IMb, flg);

    // one-time weight transpose-convert to bf16 [N][K]
    wtrans_k<<<dim3(12, 4), 256, 0, stream>>>(Wq,  WTq,  256, flg);
    wtrans_k<<<dim3(12, 4), 256, 0, stream>>>(Wk,  WTk,  256, flg);
    wtrans_k<<<dim3(12, 4), 256, 0, stream>>>(Wv,  WTv,  256, flg);
    wtrans_k<<<dim3(12, 6), 256, 0, stream>>>(Wq2, WTq2, 384, flg);
    wtrans_k<<<dim3(12, 6), 256, 0, stream>>>(Wk2, WTk2, 384, flg);
    wtrans_k<<<dim3(12, 12), 256, 0, stream>>>(Wv2, WTv2, 768, flg);
    wtrans_k<<<dim3(12, 12), 256, 0, stream>>>(Wo2, WTo2, 768, flg);
    wtrans_k<<<dim3(12, 12), 256, 0, stream>>>(Wf,  WTf,  768, flg);

    // cross-attn Q/K projections (persistent, bf16 head layout)
    cvt2b_k<<<EB, 256, 0, stream>>>(encod, Eb, NELEM, flg);
    mgemm_k<<<mGrid, 256, 0, stream>>>(Eb,       768, WTq2, 384, bq2, Q2h, 0, 1, flg);
    mgemm_k<<<mGrid, 256, 0, stream>>>(Eb + 384, 768, WTk2, 384, bk2, K2h, 0, 1, flg);

    for (int it = 0; it < 2; it++) {
        // self-attn projections (bf16 MFMA, relu, head layout)
        mgemm_k<<<mGrid, 256, 0, stream>>>(IMb,       768, WTq, 256, bq, Qbh, 1, 1, flg);
        mgemm_k<<<mGrid, 256, 0, stream>>>(IMb + 256, 768, WTk, 256, bk, Kbh, 1, 1, flg);
        mgemm_k<<<mGrid, 256, 0, stream>>>(IMb + 512, 768, WTv, 256, bv, Vbh, 1, 1, flg);
        cvtT_vb_k<<<aGrid, 256, 0, stream>>>(Vbh, Vth);
        // sa -> T1f fp32
        mfma_attn_fo_k<<<aGrid, 256, 0, stream>>>(Qbh, Kbh, Vth, T1f, scale1, 0);
        // t = bn(IM + sa) -> Tf fp32 + Tb bf16
        bnstat_f<<<bnGridF, 256, 0, stream>>>(IMf, T1f, fpart);
        bnfin_k<<<3, 256, 0, stream>>>(fpart, fstats);
        bnapply_k<<<EB, 256, 0, stream>>>(IMf, T1f, fstats, g1, b1, Tf, Tb, NELEM, flg);
        // V2 = t @ Wv2 (head layout) -> transpose -> cross attn (bf16 out for Wo2 GEMM)
        mgemm_k<<<mGrid, 256, 0, stream>>>(Tb, 768, WTv2, 768, bv2, Vbh, 0, 1, flg);
        cvtT_vb_k<<<aGrid, 256, 0, stream>>>(Vbh, Vth);
        mfma_attn_fo_k<<<aGrid, 256, 0, stream>>>(Q2h, K2h, Vth, A2b, scale2, 1);
        // m2 = attn2 @ Wo2 -> fp32
        mgemm_k<<<mGrid, 256, 0, stream>>>(A2b, 768, WTo2, 768, bo2, T2f, 0, 2, flg);
        // t2 = bn(m2 + t) -> Uf fp32 + Ub bf16
        bnstat_f<<<bnGridF, 256, 0, stream>>>(T2f, Tf, fpart);
        bnfin_k<<<3, 256, 0, stream>>>(fpart, fstats);
        bnapply_k<<<EB, 256, 0, stream>>>(T2f, Tf, fstats, g2, b2, Uf, Ub, NELEM, flg);
        // ffn = t2 @ Wf -> fp32
        mgemm_k<<<mGrid, 256, 0, stream>>>(Ub, 768, WTf, 768, bf_, Ff, 0, 2, flg);
        // im = bn(t2 + ffn) -> IMf fp32 + IMb bf16
        bnstat_f<<<bnGridF, 256, 0, stream>>>(Uf, Ff, fpart);
        bnfin_k<<<3, 256, 0, stream>>>(fpart, fstats);
        bnapply_k<<<EB, 256, 0, stream>>>(Uf, Ff, fstats, g2, b2, IMf, IMb, NELEM, flg);
    }

    store_out_f<<<EB, 256, 0, stream>>>(IMf, d_out, NELEM, flg);
}

// Round 2
// 810.560 us; speedup vs baseline: 3.3570x; 1.0648x over previous
//
#include <hip/hip_runtime.h>
#include <hip/hip_bf16.h>

#define B 4
#define S 1024
#define D 768
#define H 12
#define HD 64
#define MROWS (B * S)          // 4096
#define NELEM (B * S * D)      // 3145728

typedef __attribute__((ext_vector_type(8))) short short8;
typedef __attribute__((ext_vector_type(4))) float f32x4;

#define MFMA16(a, b, c) __builtin_amdgcn_mfma_f32_16x16x32_bf16(a, b, c, 0, 0, 0)

// LDS XOR-swizzles (col in shorts, 8-short-chunk aligned; bijective per row)
#define SWZ64(row, col) ((col) ^ (((row) & 7) << 3))        // 64-short (128B) rows
#define SWZ32(row, col) ((col) ^ ((((row) >> 1) & 3) << 3)) // 32-short (64B) rows

static __device__ __forceinline__ float bs2f(short s) {
    unsigned int u = ((unsigned int)(unsigned short)s) << 16;
    float f;
    __builtin_memcpy(&f, &u, 4);
    return f;
}
static __device__ __forceinline__ short f2bs(float f) {
    __hip_bfloat16 h = __float2bfloat16(f);
    return __builtin_bit_cast(short, h);
}
static __device__ __forceinline__ float loadin(const void* p, size_t i, int isb) {
    return isb ? bs2f(((const short*)p)[i]) : ((const float*)p)[i];
}

// ======================= dtype detect =======================
__global__ void detect_k(const void* p, int* flag) {
    if (threadIdx.x == 0 && blockIdx.x == 0) {
        const short* hb = (const short*)p;
        int insane = 0;
        for (int i = 0; i < 512; i += 2) {
            float v = bs2f(hb[i]);
            if (!(v == v) || fabsf(v) > 1e3f || (v != 0.0f && fabsf(v) < 1e-20f)) insane++;
        }
        *flag = (insane > 64) ? 0 : 1;
    }
}

// ======================= embed + positional (dual fp32 + bf16) =======================
__global__ __launch_bounds__(256) void embed_pos_k(const int* __restrict__ x,
                                                   const void* __restrict__ embed,
                                                   float* __restrict__ outf,
                                                   short* __restrict__ outb,
                                                   const int* __restrict__ flg) {
    const int f = *flg;
    int bs = blockIdx.x;
    int tok = x[bs];
    int s = bs & (S - 1);
    for (int j = threadIdx.x; j < D; j += 256) {
        float e = loadin(embed, (size_t)tok * D + j, f);
        int i = j >> 1;
        float ang = (float)s * __expf(-9.210340371976184f * (2.0f * (float)i) / (float)D);
        float p = (j & 1) ? cosf(ang) : sinf(ang);
        float v = 2.0f * e + p;
        outf[bs * D + j] = v;
        outb[bs * D + j] = f2bs(v);
    }
}

// any-dtype -> bf16
__global__ __launch_bounds__(256) void cvt2b_k(const void* __restrict__ in,
                                               short* __restrict__ out, int n,
                                               const int* __restrict__ flg) {
    const int f = *flg;
    int i = blockIdx.x * 256 + threadIdx.x;
    if (i < n) out[i] = f2bs(loadin(in, i, f));
}

// final store: fp32 state -> out dtype per flag
__global__ __launch_bounds__(256) void store_out_f(const float* __restrict__ in,
                                                   void* __restrict__ out, int n,
                                                   const int* __restrict__ flg) {
    const int f = *flg;
    int i = blockIdx.x * 256 + threadIdx.x;
    if (i < n) {
        if (f) ((short*)out)[i] = f2bs(in[i]);
        else   ((float*)out)[i] = in[i];
    }
}

// ======================= weight transpose-convert: W[K][768] -> WT bf16 [768][K] =======================
__global__ __launch_bounds__(256) void wtrans_k(const void* __restrict__ src,
                                                short* __restrict__ dst, int K,
                                                const int* __restrict__ flg) {
    const int f = *flg;
    __shared__ __align__(16) short Ts[64 * 72];
    int n0 = blockIdx.x * 64;
    int k0 = blockIdx.y * 64;
    int t = threadIdx.x;
    int r = t >> 2, c4 = (t & 3) * 16;
    #pragma unroll
    for (int j = 0; j < 16; j++)
        Ts[r * 72 + c4 + j] = f2bs(loadin(src, (size_t)(k0 + r) * D + n0 + c4 + j, f));
    __syncthreads();
    int n = t >> 2, kc = (t & 3) * 16;
    short tmp[16];
    #pragma unroll
    for (int j = 0; j < 16; j++) tmp[j] = Ts[(kc + j) * 72 + n];
    short* dchunk = dst + (size_t)(n0 + n) * K + k0 + kc;
    *(short8*)&dchunk[0] = *(const short8*)&tmp[0];
    *(short8*)&dchunk[8] = *(const short8*)&tmp[8];
}

// ======================= bf16 V [B,H,S,64] -> [B,H,64,S] =======================
// grid: (B*H, S/64) — bh fastest so all s-tiles of one head share an XCD
__global__ __launch_bounds__(256) void cvtT_vb_k(const short* __restrict__ in,
                                                 short* __restrict__ out) {
    __shared__ __align__(16) short Ts[64 * 72];
    int s0 = blockIdx.y * 64;
    int bh = blockIdx.x;
    int t = threadIdx.x;
    int r = t >> 2, c4 = (t & 3) * 16;
    const short* src = in + ((size_t)bh * S + s0 + r) * HD + c4;
    *(short8*)&Ts[r * 72 + c4] = *(const short8*)&src[0];
    *(short8*)&Ts[r * 72 + c4 + 8] = *(const short8*)&src[8];
    __syncthreads();
    int hd = t >> 2, sc = (t & 3) * 16;
    short tmp[16];
    #pragma unroll
    for (int j = 0; j < 16; j++) tmp[j] = Ts[(sc + j) * 72 + hd];
    short* dst = out + ((size_t)bh * HD + hd) * S + s0 + sc;
    *(short8*)&dst[0] = *(const short8*)&tmp[0];
    *(short8*)&dst[8] = *(const short8*)&tmp[8];
}

// ======================= MFMA GEMM (validated structure + LDS swizzle) =======================
// A bf16 [4096][lda], WT bf16 [768][K]. mode: 0=flat bf16, 1=head bf16, 2=flat fp32
__global__ __launch_bounds__(256) void mgemm_k(const short* __restrict__ A, int lda,
                                               const short* __restrict__ WT, int K,
                                               const void* __restrict__ bias,
                                               void* __restrict__ out,
                                               int relu, int mode,
                                               const int* __restrict__ flg) {
    const int f = *flg;
    __shared__ __align__(16) short As[128 * 32];
    __shared__ __align__(16) short Bs[64 * 32];
    const int t = threadIdx.x;
    const int wave = t >> 6, lane = t & 63;
    const int quad = lane >> 4, l16 = lane & 15;
    const int n0 = blockIdx.x * 64;
    const int m0 = blockIdx.y * 128;
    const int wm = (wave >> 1) * 64;
    const int wn = (wave & 1) * 32;
    f32x4 acc[4][2];
    #pragma unroll
    for (int i = 0; i < 4; i++)
        #pragma unroll
        for (int j = 0; j < 2; j++) acc[i][j] = f32x4{0.f, 0.f, 0.f, 0.f};

    const int ar0 = t >> 2;
    const int ac = (t & 3) * 8;
    const int acs = SWZ32(ar0, ac);       // same swizzle for ar0 and ar0+64 ((row>>1)&3 invariant under +64)
    const int br = t >> 2;
    for (int k0 = 0; k0 < K; k0 += 32) {
        *(short8*)&As[ar0 * 32 + acs] =
            *(const short8*)&A[(size_t)(m0 + ar0) * lda + k0 + ac];
        *(short8*)&As[(ar0 + 64) * 32 + acs] =
            *(const short8*)&A[(size_t)(m0 + ar0 + 64) * lda + k0 + ac];
        *(short8*)&Bs[br * 32 + SWZ32(br, ac)] =
            *(const short8*)&WT[(size_t)(n0 + br) * K + k0 + ac];
        __syncthreads();
        short8 af[4], bfr[2];
        #pragma unroll
        for (int i = 0; i < 4; i++) {
            int arow = wm + i * 16 + l16;
            af[i] = *(const short8*)&As[arow * 32 + SWZ32(arow, quad * 8)];
        }
        #pragma unroll
        for (int j = 0; j < 2; j++) {
            int brow = wn + j * 16 + l16;
            bfr[j] = *(const short8*)&Bs[brow * 32 + SWZ32(brow, quad * 8)];
        }
        #pragma unroll
        for (int i = 0; i < 4; i++)
            #pragma unroll
            for (int j = 0; j < 2; j++)
                acc[i][j] = MFMA16(af[i], bfr[j], acc[i][j]);
        __syncthreads();
    }
    #pragma unroll
    for (int j = 0; j < 2; j++) {
        int col = n0 + wn + j * 16 + l16;
        float bv = loadin(bias, col, f);
        #pragma unroll
        for (int i = 0; i < 4; i++) {
            int rowb = m0 + wm + i * 16 + quad * 4;
            #pragma unroll
            for (int r = 0; r < 4; r++) {
                float v = acc[i][j][r] + bv;
                if (relu) v = fmaxf(v, 0.f);
                int row = rowb + r;
                if (mode == 2) {
                    ((float*)out)[(size_t)row * D + col] = v;
                } else if (mode == 1) {
                    size_t idx = (((size_t)(row >> 10) * H + (col >> 6)) * S + (row & (S - 1))) * HD + (col & 63);
                    ((short*)out)[idx] = f2bs(v);
                } else {
                    ((short*)out)[(size_t)row * D + col] = f2bs(v);
                }
            }
        }
    }
}

// ======================= batch-norm =======================
__global__ __launch_bounds__(256) void bnstat_f(const float* __restrict__ a,
                                                const float* __restrict__ b,
                                                float* __restrict__ part) {
    __shared__ float ls[8][32];
    __shared__ float ls2[8][32];
    int f = blockIdx.x * 32 + (threadIdx.x & 31);
    int rg = threadIdx.x >> 5;
    int r0 = blockIdx.y * 256;
    float s = 0.f, s2 = 0.f;
    for (int r = r0 + rg; r < r0 + 256; r += 8) {
        float v = a[(size_t)r * D + f] + b[(size_t)r * D + f];
        s += v;
        s2 += v * v;
    }
    ls[rg][threadIdx.x & 31] = s;
    ls2[rg][threadIdx.x & 31] = s2;
    __syncthreads();
    if (threadIdx.x < 32) {
        float ts = 0.f, ts2 = 0.f;
        #pragma unroll
        for (int i = 0; i < 8; i++) { ts += ls[i][threadIdx.x]; ts2 += ls2[i][threadIdx.x]; }
        part[blockIdx.y * D + blockIdx.x * 32 + threadIdx.x] = ts;
        part[16 * D + blockIdx.y * D + blockIdx.x * 32 + threadIdx.x] = ts2;
    }
}

__global__ __launch_bounds__(256) void bnfin_k(const float* __restrict__ part,
                                               float* __restrict__ stats) {
    int f = blockIdx.x * 256 + threadIdx.x;
    if (f < D) {
        float s = 0.f, s2 = 0.f;
        #pragma unroll
        for (int i = 0; i < 16; i++) { s += part[i * D + f]; s2 += part[16 * D + i * D + f]; }
        float mean = s * (1.0f / (float)MROWS);
        float var = s2 * (1.0f / (float)MROWS) - mean * mean;
        stats[f] = mean;
        stats[D + f] = rsqrtf(var + 1e-5f);
    }
}

// dual-output bn apply: fp32 master + bf16 operand copy
__global__ __launch_bounds__(256) void bnapply_k(const float* __restrict__ a,
                                                 const float* __restrict__ b,
                                                 const float* __restrict__ stats,
                                                 const void* __restrict__ g,
                                                 const void* __restrict__ beta,
                                                 float* __restrict__ outf,
                                                 short* __restrict__ outb, int n,
                                                 const int* __restrict__ flg) {
    const int fl = *flg;
    int i = blockIdx.x * 256 + threadIdx.x;
    if (i < n) {
        int f = i % D;
        float v = a[i] + b[i];
        float y = (v - stats[f]) * stats[D + f] * loadin(g, f, fl) + loadin(beta, f, fl);
        outf[i] = y;
        outb[i] = f2bs(y);
    }
}

// ======================= MFMA flash attention (bf16 in; fp32 or bf16 out) =======================
// grid: (B*H, S/64) — bh fastest so all q-tiles of one head share an XCD (K/V L2-resident)
__global__ __launch_bounds__(256) void mfma_attn_fo_k(const short* __restrict__ Q,
                                                      const short* __restrict__ Km,
                                                      const short* __restrict__ Vt,
                                                      void* __restrict__ out, float scale,
                                                      int obf) {
    __shared__ __align__(16) short Ks[64 * 64];
    __shared__ __align__(16) short Vs[64 * 64];
    __shared__ __align__(16) short Ps[4][16 * 72];
    const int qt = blockIdx.y;
    const int bh = blockIdx.x;
    const int b = bh / H, h = bh % H;
    const int t = threadIdx.x;
    const int wave = t >> 6, lane = t & 63, quad = lane >> 4, l16 = lane & 15;
    const short* Qh = Q + (size_t)bh * S * HD;
    const short* Kh = Km + (size_t)bh * S * HD;
    const short* Vh = Vt + (size_t)bh * S * HD;
    const int qrow = qt * 64 + wave * 16 + l16;
    short8 qf0 = *(const short8*)&Qh[(size_t)qrow * 64 + quad * 8];
    short8 qf1 = *(const short8*)&Qh[(size_t)qrow * 64 + 32 + quad * 8];
    f32x4 o[4];
    float m_i[4], l_i[4];
    #pragma unroll
    for (int nt = 0; nt < 4; nt++) o[nt] = f32x4{0.f, 0.f, 0.f, 0.f};
    #pragma unroll
    for (int r = 0; r < 4; r++) { m_i[r] = -1e30f; l_i[r] = 0.f; }
    const int vhd = t >> 2, vkc = (t & 3) * 16;
    const int krow = t >> 2, kc0 = (t & 3) * 16;

    for (int kt = 0; kt < S; kt += 64) {
        const short* ksrc = &Kh[(size_t)(kt + krow) * 64 + kc0];
        *(short8*)&Ks[krow * 64 + SWZ64(krow, kc0)]     = *(const short8*)&ksrc[0];
        *(short8*)&Ks[krow * 64 + SWZ64(krow, kc0 + 8)] = *(const short8*)&ksrc[8];
        const short* vsrc = &Vh[(size_t)vhd * S + kt + vkc];
        *(short8*)&Vs[vhd * 64 + SWZ64(vhd, vkc)]     = *(const short8*)&vsrc[0];
        *(short8*)&Vs[vhd * 64 + SWZ64(vhd, vkc + 8)] = *(const short8*)&vsrc[8];
        __syncthreads();
        f32x4 sf[4];
        #pragma unroll
        for (int nt = 0; nt < 4; nt++) {
            int kr = nt * 16 + l16;
            short8 kb0 = *(const short8*)&Ks[kr * 64 + SWZ64(kr, quad * 8)];
            short8 kb1 = *(const short8*)&Ks[kr * 64 + SWZ64(kr, 32 + quad * 8)];
            f32x4 c = f32x4{0.f, 0.f, 0.f, 0.f};
            c = MFMA16(qf0, kb0, c);
            c = MFMA16(qf1, kb1, c);
            #pragma unroll
            for (int r = 0; r < 4; r++) c[r] *= scale;
            sf[nt] = c;
        }
        #pragma unroll
        for (int r = 0; r < 4; r++) {
            float mx = fmaxf(fmaxf(sf[0][r], sf[1][r]), fmaxf(sf[2][r], sf[3][r]));
            mx = fmaxf(mx, __shfl_xor(mx, 1));
            mx = fmaxf(mx, __shfl_xor(mx, 2));
            mx = fmaxf(mx, __shfl_xor(mx, 4));
            mx = fmaxf(mx, __shfl_xor(mx, 8));
            float mnew = fmaxf(m_i[r], mx);
            float alpha = __expf(m_i[r] - mnew);
            m_i[r] = mnew;
            float rs = 0.f;
            #pragma unroll
            for (int nt = 0; nt < 4; nt++) {
                float p = __expf(sf[nt][r] - mnew);
                sf[nt][r] = p;
                rs += p;
            }
            rs += __shfl_xor(rs, 1);
            rs += __shfl_xor(rs, 2);
            rs += __shfl_xor(rs, 4);
            rs += __shfl_xor(rs, 8);
            l_i[r] = l_i[r] * alpha + rs;
            #pragma unroll
            for (int nt = 0; nt < 4; nt++) o[nt][r] *= alpha;
        }
        #pragma unroll
        for (int nt = 0; nt < 4; nt++)
            #pragma unroll
            for (int r = 0; r < 4; r++)
                Ps[wave][(quad * 4 + r) * 72 + nt * 16 + l16] = f2bs(sf[nt][r]);
        short8 pa0 = *(const short8*)&Ps[wave][l16 * 72 + quad * 8];
        short8 pa1 = *(const short8*)&Ps[wave][l16 * 72 + 32 + quad * 8];
        #pragma unroll
        for (int nt = 0; nt < 4; nt++) {
            int vr = nt * 16 + l16;
            short8 vb0 = *(const short8*)&Vs[vr * 64 + SWZ64(vr, quad * 8)];
            short8 vb1 = *(const short8*)&Vs[vr * 64 + SWZ64(vr, 32 + quad * 8)];
            o[nt] = MFMA16(pa0, vb0, o[nt]);
            o[nt] = MFMA16(pa1, vb1, o[nt]);
        }
        __syncthreads();
    }
    #pragma unroll
    for (int r = 0; r < 4; r++) {
        float inv = 1.0f / l_i[r];
        int row = b * S + qt * 64 + wave * 16 + quad * 4 + r;
        #pragma unroll
        for (int nt = 0; nt < 4; nt++) {
            size_t idx = (size_t)row * D + h * HD + nt * 16 + l16;
            float v = o[nt][r] * inv;
            if (obf) ((short*)out)[idx] = f2bs(v);
            else     ((float*)out)[idx] = v;
        }
    }
}

extern "C" void kernel_launch(void* const* d_in, const int* in_sizes, int n_in,
                              void* d_out, int out_size, void* d_ws, size_t ws_size,
                              hipStream_t stream) {
    const int* x = (const int*)d_in[0];
    const short* encod = (const short*)d_in[1];
    const short* embed = (const short*)d_in[2];
    const short* Wq = (const short*)d_in[3];
    const short* bq = (const short*)d_in[4];
    const short* Wk = (const short*)d_in[5];
    const short* bk = (const short*)d_in[6];
    const short* Wv = (const short*)d_in[7];
    const short* bv = (const short*)d_in[8];
    const short* g1 = (const short*)d_in[9];
    const short* b1 = (const short*)d_in[10];
    const short* Wq2 = (const short*)d_in[11];
    const short* bq2 = (const short*)d_in[12];
    const short* Wk2 = (const short*)d_in[13];
    const short* bk2 = (const short*)d_in[14];
    const short* Wv2 = (const short*)d_in[15];
    const short* bv2 = (const short*)d_in[16];
    const short* Wo2 = (const short*)d_in[17];
    const short* bo2 = (const short*)d_in[18];
    const short* g2 = (const short*)d_in[19];
    const short* b2 = (const short*)d_in[20];
    const short* Wf = (const short*)d_in[21];
    const short* bf_ = (const short*)d_in[22];

    // ---- workspace layout in half-BUF (hb = NELEM shorts) units ----
    short* HBase = (short*)d_ws;
    #define HB(i) (HBase + (size_t)(i) * NELEM)
    float* IMf = (float*)HB(0);        // hb0-1  fp32 input_multi / final state
    short* IMb = HB(2);                // hb2    bf16 operand copy of IMf
    short* Q2h = HB(3);                // hb3    persistent cross Q (bf16 head layout)
    short* K2h = HB(4);                // hb4    persistent cross K
    short* WTp = HB(5);                // hb5    packed transposed bf16 weights
    short* WTq  = WTp;                 // [768][256]
    short* WTk  = WTp + 196608;
    short* WTv  = WTp + 393216;
    short* WTq2 = WTp + 589824;        // [768][384]
    short* WTk2 = WTp + 884736;
    short* WTv2 = WTp + 1179648;       // [768][768]
    short* WTo2 = WTp + 1769472;
    short* WTf  = WTp + 2359296;
    short* Qbh = HB(6);                // hb6    self Q (bf16 head); also Eb pre-loop; also Ub later
    short* Kbh = HB(7);                // hb7    self K
    short* Vbh = HB(8);                // hb8    V proj (head layout)
    short* Vth = HB(9);                // hb9    V transposed [B,H,64,S]
    float* T1f = (float*)HB(10);       // hb10-11 self-attn out fp32; later Uf (t2 fp32)
    float* Tf  = (float*)HB(12);       // hb12-13 t fp32
    short* Tb  = HB(14);               // hb14   t bf16
    short* A2b = HB(15);               // hb15   cross-attn out bf16
    float* T2f = (float*)HB(16);       // hb16-17 m2 fp32
    short* Eb  = Qbh;                  // pre-loop: encod bf16
    float* Uf  = T1f;                  // t2 fp32 (self-attn out dead after BN1)
    short* Ub  = Qbh;                  // t2 bf16 (Qbh dead after self-attn)
    float* Ff  = (float*)HB(8);        // ffn out fp32 (Vbh/Vth dead after cross-attn)
    float* fstats = (float*)HB(18);
    float* fpart  = fstats + 2048;
    int*   flg    = (int*)(fpart + 2 * 16 * D);

    const dim3 mGrid(D / 64, MROWS / 128);   // 12 x 32
    const dim3 bnGridF(D / 32, 16);
    const dim3 aGrid(B * H, S / 64);         // bh fastest -> XCD-local K/V
    const int EB = (NELEM + 255) / 256;
    const float scale1 = 0.03608439182435161f;   // 1/sqrt(768)
    const float scale2 = 0.125f;                 // 1/sqrt(64)

    detect_k<<<1, 64, 0, stream>>>(encod, flg);
    embed_pos_k<<<MROWS, 256, 0, stream>>>(x, embed, IMf, IMb, flg);

    // one-time weight transpose-convert to bf16 [N][K]
    wtrans_k<<<dim3(12, 4), 256, 0, stream>>>(Wq,  WTq,  256, flg);
    wtrans_k<<<dim3(12, 4), 256, 0, stream>>>(Wk,  WTk,  256, flg);
    wtrans_k<<<dim3(12, 4), 256, 0, stream>>>(Wv,  WTv,  256, flg);
    wtrans_k<<<dim3(12, 6), 256, 0, stream>>>(Wq2, WTq2, 384, flg);
    wtrans_k<<<dim3(12, 6), 256, 0, stream>>>(Wk2, WTk2, 384, flg);
    wtrans_k<<<dim3(12, 12), 256, 0, stream>>>(Wv2, WTv2, 768, flg);
    wtrans_k<<<dim3(12, 12), 256, 0, stream>>>(Wo2, WTo2, 768, flg);
    wtrans_k<<<dim3(12, 12), 256, 0, stream>>>(Wf,  WTf,  768, flg);

    // cross-attn Q/K projections (persistent, bf16 head layout)
    cvt2b_k<<<EB, 256, 0, stream>>>(encod, Eb, NELEM, flg);
    mgemm_k<<<mGrid, 256, 0, stream>>>(Eb,       768, WTq2, 384, bq2, Q2h, 0, 1, flg);
    mgemm_k<<<mGrid, 256, 0, stream>>>(Eb + 384, 768, WTk2, 384, bk2, K2h, 0, 1, flg);

    for (int it = 0; it < 2; it++) {
        // self-attn projections (bf16 MFMA, relu, head layout)
        mgemm_k<<<mGrid, 256, 0, stream>>>(IMb,       768, WTq, 256, bq, Qbh, 1, 1, flg);
        mgemm_k<<<mGrid, 256, 0, stream>>>(IMb + 256, 768, WTk, 256, bk, Kbh, 1, 1, flg);
        mgemm_k<<<mGrid, 256, 0, stream>>>(IMb + 512, 768, WTv, 256, bv, Vbh, 1, 1, flg);
        cvtT_vb_k<<<aGrid, 256, 0, stream>>>(Vbh, Vth);
        // sa -> T1f fp32
        mfma_attn_fo_k<<<aGrid, 256, 0, stream>>>(Qbh, Kbh, Vth, T1f, scale1, 0);
        // t = bn(IM + sa) -> Tf fp32 + Tb bf16
        bnstat_f<<<bnGridF, 256, 0, stream>>>(IMf, T1f, fpart);
        bnfin_k<<<3, 256, 0, stream>>>(fpart, fstats);
        bnapply_k<<<EB, 256, 0, stream>>>(IMf, T1f, fstats, g1, b1, Tf, Tb, NELEM, flg);
        // V2 = t @ Wv2 (head layout) -> transpose -> cross attn (bf16 out for Wo2 GEMM)
        mgemm_k<<<mGrid, 256, 0, stream>>>(Tb, 768, WTv2, 768, bv2, Vbh, 0, 1, flg);
        cvtT_vb_k<<<aGrid, 256, 0, stream>>>(Vbh, Vth);
        mfma_attn_fo_k<<<aGrid, 256, 0, stream>>>(Q2h, K2h, Vth, A2b, scale2, 1);
        // m2 = attn2 @ Wo2 -> fp32
        mgemm_k<<<mGrid, 256, 0, stream>>>(A2b, 768, WTo2, 768, bo2, T2f, 0, 2, flg);
        // t2 = bn(m2 + t) -> Uf fp32 + Ub bf16
        bnstat_f<<<bnGridF, 256, 0, stream>>>(T2f, Tf, fpart);
        bnfin_k<<<3, 256, 0, stream>>>(fpart, fstats);
        bnapply_k<<<EB, 256, 0, stream>>>(T2f, Tf, fstats, g2, b2, Uf, Ub, NELEM, flg);
        // ffn = t2 @ Wf -> fp32
        mgemm_k<<<mGrid, 256, 0, stream>>>(Ub, 768, WTf, 768, bf_, Ff, 0, 2, flg);
        // im = bn(t2 + ffn) -> IMf fp32 + IMb bf16
        bnstat_f<<<bnGridF, 256, 0, stream>>>(Uf, Ff, fpart);
        bnfin_k<<<3, 256, 0, stream>>>(fpart, fstats);
        bnapply_k<<<EB, 256, 0, stream>>>(Uf, Ff, fstats, g2, b2, IMf, IMb, NELEM, flg);
    }

    store_out_f<<<EB, 256, 0, stream>>>(IMf, d_out, NELEM, flg);
}